// Round 6
// baseline (66.732 us; speedup 1.0000x reference)
//
#include <hip/hip_runtime.h>
#include <hip/hip_bf16.h>

typedef __bf16 bf16x8 __attribute__((ext_vector_type(8)));
typedef float  f32x4  __attribute__((ext_vector_type(4)));

#define NTILES 16384               // 262144 rows / 16
#define NWAVES 4096                // 1024 blocks x 4 waves -> 4 tiles/wave, grid co-resident

// ---------------------------------------------------------------------------
// Kernel 1 (one-shot, 64 blocks): expand quaternion weight (32,32,4) ->
// W_eff (128x128) in bf16, MFMA A-fragment order, k-axis permuted so the main
// kernel's x loads are full-granule coalesced (verified rounds 1-5):
//   element j of fragment (nt,kb,lane) holds physical
//     k = kb*32 + (j<4 ? g*4+j : 16 + g*4 + (j-4)),  g = lane>>4
// ---------------------------------------------------------------------------
__global__ __launch_bounds__(256) void prep_wfrag(const float* __restrict__ w,
                                                  ushort* __restrict__ wfrag) {
    int t = blockIdx.x * 256 + threadIdx.x;
    if (t >= 128 * 128) return;
    int j    = t & 7;
    int lane = (t >> 3) & 63;
    int kb   = (t >> 9) & 3;
    int nt   = t >> 11;
    int g    = lane >> 4;
    int n = nt * 16 + (lane & 15);
    int k = kb * 32 + (j < 4 ? g * 4 + j : 16 + g * 4 + (j - 4));
    int o  = n >> 2, c = n & 3;
    int nq = k >> 2, d = k & 3;
    int comp = c ^ d;
    bool neg = (d != 0) && ((c == 0) || (c != d && d != (c % 3) + 1));
    float val = w[o * 128 + nq * 4 + comp];
    val = neg ? -val : val;
    __bf16 bv = (__bf16)val;
    wfrag[t] = *reinterpret_cast<ushort*>(&bv);
}

// ---------------------------------------------------------------------------
// Kernel 2: out = x @ W_eff^T + bias.  4 tiles/wave, software-pipelined:
// schedule L0 L1 C0 L2 C1 L3 C2 C3 with static rA/rB double buffer, so every
// compute's loads were issued a full compute-phase earlier (counted vmcnt(8),
// no drain, no exposed HBM latency). No barriers/clobbers in the tile stream.
// ---------------------------------------------------------------------------
__global__ __launch_bounds__(256, 4) void qgemm(const float* __restrict__ x,
                                                const ushort* __restrict__ wfrag,
                                                const float* __restrict__ bias,
                                                float* __restrict__ out) {
    __shared__ __align__(16) ushort wlds[16384];   // 32 KB fragment-ordered W
    __shared__ __align__(16) float  sbias[128];

    int tid = threadIdx.x;
    {   // setup: linear 32 KB copy (L2-hot after first blocks)
        const int4* src = (const int4*)wfrag;
        int4*       dst = (int4*)wlds;
#pragma unroll
        for (int i = 0; i < 8; ++i) dst[tid + i * 256] = src[tid + i * 256];
    }
    if (tid < 128) sbias[tid] = bias[tid];

    int lane  = tid & 63;
    int wid   = tid >> 6;      // 0..3
    int row16 = lane & 15;     // batch row within tile == D col
    int kgrp  = lane >> 4;     // 0..3
    int loff  = row16 * 128 + kgrp * 4;   // per-lane float offset within a tile

    __syncthreads();

    const bf16x8* blds = (const bf16x8*)wlds;
    int g = blockIdx.x * 4 + wid;         // 0..4095; tiles g, g+4096, g+8192, g+12288

    float4 rA[8], rB[8];

    auto load_tile = [&](float4* r, int t) {
        const float4* xv = (const float4*)(x + (size_t)t * 2048 + loff);
#pragma unroll
        for (int kb = 0; kb < 4; ++kb) {
            r[2 * kb]     = xv[kb * 8];       // floats loff + kb*32 .. +3
            r[2 * kb + 1] = xv[kb * 8 + 4];   // floats loff + kb*32+16 .. +19
        }
    };

    auto compute_tile = [&](const float4* r, int t) {
        bf16x8 afr[4];
#pragma unroll
        for (int kb = 0; kb < 4; ++kb) {
            float4 p = r[2 * kb], q = r[2 * kb + 1];
            afr[kb][0] = (__bf16)p.x; afr[kb][1] = (__bf16)p.y;
            afr[kb][2] = (__bf16)p.z; afr[kb][3] = (__bf16)p.w;
            afr[kb][4] = (__bf16)q.x; afr[kb][5] = (__bf16)q.y;
            afr[kb][6] = (__bf16)q.z; afr[kb][7] = (__bf16)q.w;
        }
        // D layout: col = lane&15 = batch row, row = kgrp*4 + reg = feature.
        float* op = out + (size_t)t * 2048 + loff;
#pragma unroll
        for (int nt = 0; nt < 8; ++nt) {
            f32x4 acc = *(const f32x4*)&sbias[nt * 16 + kgrp * 4];
#pragma unroll
            for (int kb = 0; kb < 4; ++kb) {
                bf16x8 wfr = blds[(nt * 4 + kb) * 64 + lane];
                acc = __builtin_amdgcn_mfma_f32_16x16x32_bf16(wfr, afr[kb], acc, 0, 0, 0);
            }
            *(f32x4*)(op + nt * 16) = acc;
        }
    };

    // Software pipeline: every compute has the NEXT tile's loads in flight.
    load_tile(rA, g);
    load_tile(rB, g + NWAVES);
    compute_tile(rA, g);
    load_tile(rA, g + 2 * NWAVES);
    compute_tile(rB, g + NWAVES);
    load_tile(rB, g + 3 * NWAVES);
    compute_tile(rA, g + 2 * NWAVES);
    compute_tile(rB, g + 3 * NWAVES);
}

extern "C" void kernel_launch(void* const* d_in, const int* in_sizes, int n_in,
                              void* d_out, int out_size, void* d_ws, size_t ws_size,
                              hipStream_t stream) {
    const float* x      = (const float*)d_in[0];   // [262144,128] fp32
    const float* weight = (const float*)d_in[1];   // [32,32,4] fp32
    const float* bias   = (const float*)d_in[2];   // [128] fp32
    float*       out    = (float*)d_out;           // [262144,128] fp32
    ushort*      wfrag  = (ushort*)d_ws;           // 32 KB fragment-ordered W_eff

    prep_wfrag<<<64, 256, 0, stream>>>(weight, wfrag);
    qgemm<<<1024, 256, 0, stream>>>(x, wfrag, bias, out);
}